// Round 9
// baseline (219.508 us; speedup 1.0000x reference)
//
#include <hip/hip_runtime.h>

constexpr int BS = 16;     // batch (vis and txt)
constexpr int S  = 4096;   // spatial
constexpr int E  = 128;    // embedding
constexpr int T  = 64;     // text tokens
constexpr int NSP = 4;     // s-quarters per (i,b) pair
constexpr int SSEG = S / NSP;        // 1024
constexpr int CH = 128;    // s-rows per chunk (8 waves x 16 rows)
constexpr int NCH = SSEG / CH;       // 8
constexpr int ETS = 140;   // ET stride (shorts): W=70 words == 6 mod 8 -> conflict-free
                           // scatter writes (banks 24q-spread) + conflict-free b64 reads
constexpr int TNS = 136;   // tnL stride (shorts): b128 reads 2-way (free)
constexpr int PTS = 264;   // prepass transpose-tile stride

// ws layout:
//   shorts [0 .. 8388608)        : vn [b][s][e]  normalized bf16   (16 MB)
//   shorts [8388608 .. 16777216) : vnT[b][e][s]  normalized bf16   (16 MB)
//   floats [WS_P .. WS_P+8388608): wc^T partials [pair][quarter][e][t] (33.5 MB)
//   floats [WS_SIMS .. +256)     : sims[b*16+i]
constexpr long VN_OFF  = 0;
constexpr long VNT_OFF = (long)BS * S * E;
constexpr long WS_P    = (long)BS * S * E;              // float idx == byte 32 MB
constexpr long WS_SIMS = WS_P + (long)256 * NSP * 8192; // float idx

typedef __attribute__((ext_vector_type(8))) short bf16x8;
typedef __attribute__((ext_vector_type(4))) short bf16x4;
typedef __attribute__((ext_vector_type(4))) float f32x4;

constexpr float LOG2E  = 1.4426950408889634f;
constexpr float LOG2E4 = 5.771780163555852f * (4.0f / 4.0f);  // 4*log2(e)

__device__ __forceinline__ unsigned short f2bf(float x) {
    unsigned u = __float_as_uint(x);
    u += 0x7FFFu + ((u >> 16) & 1u);          // RTNE
    return (unsigned short)(u >> 16);
}
__device__ __forceinline__ float bf2f(unsigned short v) {
    return __uint_as_float(((unsigned)v) << 16);
}
// 8B-aligned bf16x8 load from LDS (ET rows are 8B- but not 16B-aligned)
__device__ __forceinline__ bf16x8 ld_b64x2(const unsigned short* p) {
    const bf16x4 lo = *(const bf16x4*)p;
    const bf16x4 hi = *(const bf16x4*)(p + 4);
    bf16x8 r;
    r[0]=lo[0]; r[1]=lo[1]; r[2]=lo[2]; r[3]=lo[3];
    r[4]=hi[0]; r[5]=hi[1]; r[6]=hi[2]; r[7]=hi[3];
    return r;
}

// Pre-pass: normalize vis once, emit vn[s][e] and vnT[e][s] bf16. (round-5..8 proven)
__global__ __launch_bounds__(1024, 4)
void prep_kernel(const float* __restrict__ vis, unsigned short* __restrict__ wsv)
{
    __shared__ unsigned short Lt[128 * PTS];
    const int tid  = threadIdx.x;
    const int b    = blockIdx.x >> 4;
    const int tile = blockIdx.x & 15;
    const int s0   = tile * 256;
    const float* visb = vis + ((long)b * S + s0) * E;
    unsigned short* vn  = wsv + VN_OFF  + ((long)b * S + s0) * E;
    unsigned short* vnT = wsv + VNT_OFF + (long)b * E * S;

    {
        const int pp = tid >> 3, ee = tid & 7;
        const float* rA = visb + (long)(pp << 1) * E + (ee << 1);
        float2 va[8], vb[8];
        float sa = 0.f, sb = 0.f;
#pragma unroll
        for (int k = 0; k < 8; ++k) {
            va[k] = *(const float2*)(rA + (k << 4));
            vb[k] = *(const float2*)(rA + E + (k << 4));
            sa = fmaf(va[k].x, va[k].x, fmaf(va[k].y, va[k].y, sa));
            sb = fmaf(vb[k].x, vb[k].x, fmaf(vb[k].y, vb[k].y, sb));
        }
        sa += __shfl_xor(sa, 1); sa += __shfl_xor(sa, 2); sa += __shfl_xor(sa, 4);
        sb += __shfl_xor(sb, 1); sb += __shfl_xor(sb, 2); sb += __shfl_xor(sb, 4);
        const float ia = 1.0f / fmaxf(sqrtf(sa), 1e-12f);
        const float ib = 1.0f / fmaxf(sqrtf(sb), 1e-12f);
        const long r0 = (long)(pp << 1) * E, r1 = r0 + E;
#pragma unroll
        for (int k = 0; k < 8; ++k) {
            const int e0 = (ee << 1) + (k << 4);
            const unsigned ax = f2bf(va[k].x * ia), ay = f2bf(va[k].y * ia);
            const unsigned bx = f2bf(vb[k].x * ib), by = f2bf(vb[k].y * ib);
            *(unsigned*)&Lt[e0 * PTS + (pp << 1)]       = ax | (bx << 16);
            *(unsigned*)&Lt[(e0 + 1) * PTS + (pp << 1)] = ay | (by << 16);
            *(unsigned*)&vn[r0 + e0] = ax | (ay << 16);
            *(unsigned*)&vn[r1 + e0] = bx | (by << 16);
        }
    }
    __syncthreads();
    {
        const int e = tid >> 3, sseg = (tid & 7) << 5;
#pragma unroll
        for (int k = 0; k < 4; ++k) {
            const bf16x8 v = *(const bf16x8*)&Lt[e * PTS + sseg + (k << 3)];
            *(bf16x8*)&vnT[(long)e * S + s0 + sseg + (k << 3)] = v;
        }
    }
}

// Main: 1024 blocks = (i,b) x s-quarter. 512 threads = 8 waves.
__global__ __launch_bounds__(512, 4)
void clip_main_kernel(const unsigned short* __restrict__ wsv,
                      const float* __restrict__ txt,
                      float* __restrict__ d_out,
                      float* __restrict__ wsf)
{
    __shared__ unsigned short ET[T * ETS];     // 17.9 KB
    __shared__ unsigned short tnL[T * TNS];    // 17.4 KB

    const int tid = threadIdx.x;
    const int w   = tid >> 6;       // wave 0..7
    const int l   = tid & 63;
    const int cl  = l & 15;
    const int q   = l >> 4;
    const int b   = blockIdx.x & 15;
    const int i   = (blockIdx.x >> 4) & 15;
    const int qt  = blockIdx.x >> 8;          // s-quarter 0..3
    const bool diag = (i == b);

    // ---- stage tn (normalized bf16) into LDS: row=tid>>3, 16-e seg=tid&7 ----
    {
        const int r = tid >> 3, seg = tid & 7;
        const float* tp = txt + ((long)i * T + r) * E + (seg << 4);
        const float4 a0 = *(const float4*)(tp);
        const float4 a1 = *(const float4*)(tp + 4);
        const float4 a2 = *(const float4*)(tp + 8);
        const float4 a3 = *(const float4*)(tp + 12);
        float ssq = a0.x*a0.x + a0.y*a0.y + a0.z*a0.z + a0.w*a0.w
                  + a1.x*a1.x + a1.y*a1.y + a1.z*a1.z + a1.w*a1.w
                  + a2.x*a2.x + a2.y*a2.y + a2.z*a2.z + a2.w*a2.w
                  + a3.x*a3.x + a3.y*a3.y + a3.z*a3.z + a3.w*a3.w;
        ssq += __shfl_xor(ssq, 1); ssq += __shfl_xor(ssq, 2); ssq += __shfl_xor(ssq, 4);
        const float inv = 1.0f / fmaxf(sqrtf(ssq), 1e-12f);
        bf16x8 f0, f1;
        f0[0]=(short)f2bf(a0.x*inv); f0[1]=(short)f2bf(a0.y*inv);
        f0[2]=(short)f2bf(a0.z*inv); f0[3]=(short)f2bf(a0.w*inv);
        f0[4]=(short)f2bf(a1.x*inv); f0[5]=(short)f2bf(a1.y*inv);
        f0[6]=(short)f2bf(a1.z*inv); f0[7]=(short)f2bf(a1.w*inv);
        f1[0]=(short)f2bf(a2.x*inv); f1[1]=(short)f2bf(a2.y*inv);
        f1[2]=(short)f2bf(a2.z*inv); f1[3]=(short)f2bf(a2.w*inv);
        f1[4]=(short)f2bf(a3.x*inv); f1[5]=(short)f2bf(a3.y*inv);
        f1[6]=(short)f2bf(a3.z*inv); f1[7]=(short)f2bf(a3.w*inv);
        *(bf16x8*)&tnL[r * TNS + (seg << 4)]     = f0;
        *(bf16x8*)&tnL[r * TNS + (seg << 4) + 8] = f1;
    }
    __syncthreads();

    // ---- hoist tA m-tiles 0,1 to regs (16 VGPRs); tiles 2,3 stay in LDS ----
    bf16x8 tA0[2][4];
#pragma unroll
    for (int mt = 0; mt < 2; ++mt)
#pragma unroll
        for (int kk = 0; kk < 4; ++kk)
            tA0[mt][kk] = *(const bf16x8*)&tnL[((mt << 4) + cl) * TNS + (kk << 5) + (q << 3)];

    f32x4 acc2[4];   // wc^T: e = w*16+q*4+r, t = n*16+cl
#pragma unroll
    for (int n = 0; n < 4; ++n) acc2[n] = (f32x4){0.f,0.f,0.f,0.f};

    const unsigned short* vnb  = wsv + VN_OFF  + (long)b * S * E;
    const unsigned short* vntb = wsv + VNT_OFF + (long)b * E * S;
    float* attb = d_out + 1 + (long)b * (long)T * S;

    for (int ch = 0; ch < NCH; ++ch) {
        const int s0 = qt * SSEG + ch * CH;

        // ---- GEMM1 B-loads (global bf16, L2-hot) ----
        bf16x8 Bf[4];
        {
            const unsigned short* r0 = vnb + (long)(s0 + (w << 4) + cl) * E + (q << 3);
#pragma unroll
            for (int kk = 0; kk < 4; ++kk) Bf[kk] = *(const bf16x8*)(r0 + (kk << 5));
        }

        // ---- GEMM1 (tiles 0,1 from regs; 2,3 from LDS) + softmax -> ET ----
        {
            f32x4 acc1[4];
#pragma unroll
            for (int mt = 0; mt < 4; ++mt) acc1[mt] = (f32x4){0.f,0.f,0.f,0.f};
#pragma unroll
            for (int kk = 0; kk < 4; ++kk) {
                acc1[0] = __builtin_amdgcn_mfma_f32_16x16x32_bf16(tA0[0][kk], Bf[kk], acc1[0], 0, 0, 0);
                acc1[1] = __builtin_amdgcn_mfma_f32_16x16x32_bf16(tA0[1][kk], Bf[kk], acc1[1], 0, 0, 0);
                const bf16x8 t2 = *(const bf16x8*)&tnL[(32 + cl) * TNS + (kk << 5) + (q << 3)];
                const bf16x8 t3 = *(const bf16x8*)&tnL[(48 + cl) * TNS + (kk << 5) + (q << 3)];
                acc1[2] = __builtin_amdgcn_mfma_f32_16x16x32_bf16(t2, Bf[kk], acc1[2], 0, 0, 0);
                acc1[3] = __builtin_amdgcn_mfma_f32_16x16x32_bf16(t3, Bf[kk], acc1[3], 0, 0, 0);
            }
            float ex[4][4];
            float ssum = 0.f;
#pragma unroll
            for (int mt = 0; mt < 4; ++mt)
#pragma unroll
                for (int r = 0; r < 4; ++r) {
                    const float v = exp2f(acc1[mt][r] * LOG2E);  // exp(logit), |logit|<=~1
                    ex[mt][r] = v; ssum += v;
                }
            ssum += __shfl_xor(ssum, 16);
            ssum += __shfl_xor(ssum, 32);
            const float csc = LOG2E4 / ssum;   // e = exp(4*ex/ssum) = exp2(ex*csc)
            const int sloc = (w << 4) + cl;
#pragma unroll
            for (int mt = 0; mt < 4; ++mt)
#pragma unroll
                for (int r = 0; r < 4; ++r)
                    ET[((mt << 4) + (q << 2) + r) * ETS + sloc] = f2bf(exp2f(ex[mt][r] * csc));
        }
        __syncthreads();

        // ---- GEMM2: wc^T += vnT (global b128) x ET (LDS b64 pairs) ----
        {
            const unsigned short* ar = vntb + (long)((w << 4) + cl) * S + s0 + (q << 3);
#pragma unroll
            for (int kk2 = 0; kk2 < 4; ++kk2) {
                const bf16x8 aV = *(const bf16x8*)(ar + (kk2 << 5));
#pragma unroll
                for (int n = 0; n < 4; ++n) {
                    const bf16x8 bE = ld_b64x2(&ET[((n << 4) + cl) * ETS + (kk2 << 5) + (q << 3)]);
                    acc2[n] = __builtin_amdgcn_mfma_f32_16x16x32_bf16(aV, bE, acc2[n], 0, 0, 0);
                }
            }
        }

        // ---- diag: dump unnormalized e (att_norm self-normalizes) ----
        if (diag) {
            const int t = tid >> 3, sg = (tid & 7) << 4;
            float* ap = attb + (long)t * S + s0 + sg;
            const bf16x8 v0 = ld_b64x2(&ET[t * ETS + sg]);
            const bf16x8 v1 = ld_b64x2(&ET[t * ETS + sg + 8]);
#pragma unroll
            for (int j = 0; j < 8; ++j) {
                ap[j]     = bf2f((unsigned short)v0[j]);
                ap[8 + j] = bf2f((unsigned short)v1[j]);
            }
        }
        __syncthreads();
    }

    // ---- store wc^T partials (disjoint per (pair, quarter) — no atomics) ----
    {
        float* pp = wsf + WS_P + ((long)(((i << 4) + b) << 2) + qt) * 8192;
#pragma unroll
        for (int n = 0; n < 4; ++n)
#pragma unroll
            for (int r = 0; r < 4; ++r)
                pp[((w << 4) + (q << 2) + r) * 64 + (n << 4) + cl] = acc2[n][r];
    }
}

// One block per pair: sum 4 quarters, cos over E, LSE over t -> sims.
__global__ __launch_bounds__(256, 8)
void reduce_kernel(const float* __restrict__ txt, float* __restrict__ wsf)
{
    __shared__ float sA[256], sB[256], sC[256];
    const int tid = threadIdx.x;
    const int t = tid & 63, w4 = tid >> 6;
    const int pair = blockIdx.x;
    const int i = pair >> 4, b = pair & 15;
    const float* p0 = wsf + WS_P + (long)pair * NSP * 8192;
    const float* tp = txt + ((long)i * T + t) * E + (w4 << 5);

    float ssq = 0.f, num = 0.f, w2 = 0.f;
#pragma unroll 8
    for (int e = 0; e < 32; ++e) {
        const float tv = tp[e];
        const int idx = ((w4 << 5) + e) * 64 + t;
        const float wc = p0[idx] + p0[idx + 8192] + p0[idx + 16384] + p0[idx + 24576];
        ssq = fmaf(tv, tv, ssq);
        num = fmaf(wc, tv, num);
        w2  = fmaf(wc, wc, w2);
    }
    sA[tid] = ssq; sB[tid] = num; sC[tid] = w2;
    __syncthreads();
    if (tid < 64) {
        const float ss = sA[tid] + sA[64 + tid] + sA[128 + tid] + sA[192 + tid];
        const float nm = sB[tid] + sB[64 + tid] + sB[128 + tid] + sB[192 + tid];
        const float ww = sC[tid] + sC[64 + tid] + sC[128 + tid] + sC[192 + tid];
        const float cosv = (nm / fmaxf(sqrtf(ss), 1e-12f)) / fmaxf(sqrtf(ww), 1e-20f);
        float r = __expf(5.0f * cosv);
#pragma unroll
        for (int m = 1; m < 64; m <<= 1) r += __shfl_xor(r, m);
        if (tid == 0) wsf[WS_SIMS + (b << 4) + i] = 10.0f * logf(r);
    }
}

// Blocks 0..1023: att row (b,t) self-normalize. Block 1024: 16x16 loss.
__global__ __launch_bounds__(256, 4)
void att_norm_loss_kernel(float* __restrict__ d_out, const float* __restrict__ wsf)
{
    const int tid = threadIdx.x;
    if (blockIdx.x == BS * T) {
        __shared__ float sm[16][17];
        __shared__ float red[16];
        const int bb = tid >> 4, ii = tid & 15;
        const float x = wsf[WS_SIMS + bb * 16 + ii];
        sm[bb][ii] = x;
        float m = x;
#pragma unroll
        for (int msk = 1; msk < 16; msk <<= 1) m = fmaxf(m, __shfl_xor(m, msk));
        float s = __expf(x - m);
#pragma unroll
        for (int msk = 1; msk < 16; msk <<= 1) s += __shfl_xor(s, msk);
        const float lsm0 = x - m - logf(s);
        __syncthreads();
        const float y = sm[ii][bb];
        float m1 = y;
#pragma unroll
        for (int msk = 1; msk < 16; msk <<= 1) m1 = fmaxf(m1, __shfl_xor(m1, msk));
        float s1 = __expf(y - m1);
#pragma unroll
        for (int msk = 1; msk < 16; msk <<= 1) s1 += __shfl_xor(s1, msk);
        const float lsm1 = y - m1 - logf(s1);
        if (bb == ii) red[bb] = lsm0 + lsm1;
        __syncthreads();
        if (tid == 0) {
            float tot = 0.f;
#pragma unroll
            for (int k = 0; k < 16; ++k) tot += red[k];
            d_out[0] = -tot / 32.0f;
        }
        return;
    }
    __shared__ float r4[4];
    const int bt = blockIdx.x;
    float* p = d_out + 1 + (long)bt * 4096;
    float v[16];
    float s = 0.f;
#pragma unroll
    for (int k = 0; k < 16; ++k) { v[k] = p[k * 256 + tid]; s += v[k]; }
#pragma unroll
    for (int m = 1; m < 64; m <<= 1) s += __shfl_xor(s, m);
    if ((tid & 63) == 0) r4[tid >> 6] = s;
    __syncthreads();
    const float inv = 1.0f / (r4[0] + r4[1] + r4[2] + r4[3]);
#pragma unroll
    for (int k = 0; k < 16; ++k) p[k * 256 + tid] = v[k] * inv;
}

extern "C" void kernel_launch(void* const* d_in, const int* in_sizes, int n_in,
                              void* d_out, int out_size, void* d_ws, size_t ws_size,
                              hipStream_t stream)
{
    const float* vis = (const float*)d_in[0];
    const float* txt = (const float*)d_in[1];
    float* out = (float*)d_out;
    unsigned short* wsv = (unsigned short*)d_ws;
    float* wsf = (float*)d_ws;

    hipLaunchKernelGGL(prep_kernel, dim3(256), dim3(1024), 0, stream, vis, wsv);
    hipLaunchKernelGGL(clip_main_kernel, dim3(BS * BS * NSP), dim3(512), 0, stream,
                       wsv, txt, out, wsf);
    hipLaunchKernelGGL(reduce_kernel, dim3(BS * BS), dim3(256), 0, stream, txt, wsf);
    hipLaunchKernelGGL(att_norm_loss_kernel, dim3(BS * T + 1), dim3(256), 0, stream,
                       out, wsf);
}

// Round 10
// 193.812 us; speedup vs baseline: 1.1326x; 1.1326x over previous
//
#include <hip/hip_runtime.h>

constexpr int BS = 16;     // batch (vis and txt)
constexpr int S  = 4096;   // spatial
constexpr int E  = 128;    // embedding
constexpr int T  = 64;     // text tokens
constexpr int NSP = 4;     // s-quarters per (i,b) pair
constexpr int SSEG = S / NSP;        // 1024
constexpr int CH = 128;    // s-rows per chunk (8 waves x 16 rows)
constexpr int NCH = SSEG / CH;       // 8
constexpr int ETS = 136;   // ET stride (shorts): rows 16B-aligned, b128 reads bank-optimal
                           // (round-8 proven; round-9's b64 variant regressed)
constexpr int TNS = 136;   // tnL stride (shorts)
constexpr int PTS = 264;   // prep transpose-tile stride (round-5 proven)

// ws layout:
//   shorts [0 .. 8388608)        : vn [b][s][e]  normalized bf16   (16 MB)
//   shorts [8388608 .. 16777216) : vnT[b][e][s]  normalized bf16   (16 MB)
//   floats [WS_P .. WS_P+8388608): wc^T partials [pair][quarter][e][t] (33.5 MB)
//   floats [WS_SIMS .. +256)     : sims[b*16+i]
constexpr long VN_OFF  = 0;
constexpr long VNT_OFF = (long)BS * S * E;
constexpr long WS_P    = (long)BS * S * E;              // float idx == byte 32 MB
constexpr long WS_SIMS = WS_P + (long)256 * NSP * 8192; // float idx

typedef __attribute__((ext_vector_type(8))) short bf16x8;
typedef __attribute__((ext_vector_type(4))) float f32x4;

__device__ __forceinline__ unsigned short f2bf(float x) {
    unsigned u = __float_as_uint(x);
    u += 0x7FFFu + ((u >> 16) & 1u);          // RTNE
    return (unsigned short)(u >> 16);
}
__device__ __forceinline__ float bf2f(unsigned short v) {
    return __uint_as_float(((unsigned)v) << 16);
}

// Pre-pass v2: 512 blocks = b x 32 s-tiles (128 rows), 512 threads -> 2 blocks/CU.
// Same proven access pattern as rounds 5-9, double the parallelism.
__global__ __launch_bounds__(512, 2)
void prep_kernel(const float* __restrict__ vis, unsigned short* __restrict__ wsv)
{
    __shared__ unsigned short Lt[128 * PTS];   // 67.6 KB -> 2 blocks/CU
    const int tid  = threadIdx.x;
    const int b    = blockIdx.x >> 5;
    const int tile = blockIdx.x & 31;
    const int s0   = tile * 128;
    const float* visb = vis + ((long)b * S + s0) * E;
    unsigned short* vn  = wsv + VN_OFF  + ((long)b * S + s0) * E;
    unsigned short* vnT = wsv + VNT_OFF + (long)b * E * S;

    // phase 1: load fp32 row-pairs, normalize, write vn + packed transpose into Lt
    {
        const int pp = tid >> 3, ee = tid & 7;   // row-pairs 0..63, e-pair lanes 0..7
        const float* rA = visb + (long)(pp << 1) * E + (ee << 1);
        float2 va[8], vb[8];
        float sa = 0.f, sb = 0.f;
#pragma unroll
        for (int k = 0; k < 8; ++k) {
            va[k] = *(const float2*)(rA + (k << 4));
            vb[k] = *(const float2*)(rA + E + (k << 4));
            sa = fmaf(va[k].x, va[k].x, fmaf(va[k].y, va[k].y, sa));
            sb = fmaf(vb[k].x, vb[k].x, fmaf(vb[k].y, vb[k].y, sb));
        }
        sa += __shfl_xor(sa, 1); sa += __shfl_xor(sa, 2); sa += __shfl_xor(sa, 4);
        sb += __shfl_xor(sb, 1); sb += __shfl_xor(sb, 2); sb += __shfl_xor(sb, 4);
        const float ia = 1.0f / fmaxf(sqrtf(sa), 1e-12f);
        const float ib = 1.0f / fmaxf(sqrtf(sb), 1e-12f);
        const long r0 = (long)(pp << 1) * E, r1 = r0 + E;
#pragma unroll
        for (int k = 0; k < 8; ++k) {
            const int e0 = (ee << 1) + (k << 4);
            const unsigned ax = f2bf(va[k].x * ia), ay = f2bf(va[k].y * ia);
            const unsigned bx = f2bf(vb[k].x * ib), by = f2bf(vb[k].y * ib);
            *(unsigned*)&Lt[e0 * PTS + (pp << 1)]       = ax | (bx << 16);
            *(unsigned*)&Lt[(e0 + 1) * PTS + (pp << 1)] = ay | (by << 16);
            *(unsigned*)&vn[r0 + e0] = ax | (ay << 16);
            *(unsigned*)&vn[r1 + e0] = bx | (by << 16);
        }
    }
    __syncthreads();
    // phase 2: coalesced dump Lt -> vnT[e][s] (e = tid>>2, 32 s per thread)
    {
        const int e = tid >> 2, sseg = (tid & 3) << 5;
#pragma unroll
        for (int k = 0; k < 4; ++k) {
            const bf16x8 v = *(const bf16x8*)&Lt[e * PTS + sseg + (k << 3)];
            *(bf16x8*)&vnT[(long)e * S + s0 + sseg + (k << 3)] = v;
        }
    }
}

// Main: 1024 blocks = (i,b) x s-quarter. 512 threads = 8 waves. (round-8 exact)
__global__ __launch_bounds__(512, 4)
void clip_main_kernel(const unsigned short* __restrict__ wsv,
                      const float* __restrict__ txt,
                      float* __restrict__ d_out,
                      float* __restrict__ wsf)
{
    __shared__ unsigned short ET[T * ETS];     // 17.4 KB
    __shared__ unsigned short tnL[T * TNS];    // 17.4 KB

    const int tid = threadIdx.x;
    const int w   = tid >> 6;       // wave 0..7
    const int l   = tid & 63;
    const int cl  = l & 15;
    const int q   = l >> 4;
    const int b   = blockIdx.x & 15;
    const int i   = (blockIdx.x >> 4) & 15;
    const int qt  = blockIdx.x >> 8;          // s-quarter 0..3
    const bool diag = (i == b);

    // ---- stage tn (normalized bf16) into LDS: row=tid>>3, 16-e seg=tid&7 ----
    {
        const int r = tid >> 3, seg = tid & 7;
        const float* tp = txt + ((long)i * T + r) * E + (seg << 4);
        const float4 a0 = *(const float4*)(tp);
        const float4 a1 = *(const float4*)(tp + 4);
        const float4 a2 = *(const float4*)(tp + 8);
        const float4 a3 = *(const float4*)(tp + 12);
        float ssq = a0.x*a0.x + a0.y*a0.y + a0.z*a0.z + a0.w*a0.w
                  + a1.x*a1.x + a1.y*a1.y + a1.z*a1.z + a1.w*a1.w
                  + a2.x*a2.x + a2.y*a2.y + a2.z*a2.z + a2.w*a2.w
                  + a3.x*a3.x + a3.y*a3.y + a3.z*a3.z + a3.w*a3.w;
        ssq += __shfl_xor(ssq, 1); ssq += __shfl_xor(ssq, 2); ssq += __shfl_xor(ssq, 4);
        const float inv = 1.0f / fmaxf(sqrtf(ssq), 1e-12f);
        bf16x8 f0, f1;
        f0[0]=(short)f2bf(a0.x*inv); f0[1]=(short)f2bf(a0.y*inv);
        f0[2]=(short)f2bf(a0.z*inv); f0[3]=(short)f2bf(a0.w*inv);
        f0[4]=(short)f2bf(a1.x*inv); f0[5]=(short)f2bf(a1.y*inv);
        f0[6]=(short)f2bf(a1.z*inv); f0[7]=(short)f2bf(a1.w*inv);
        f1[0]=(short)f2bf(a2.x*inv); f1[1]=(short)f2bf(a2.y*inv);
        f1[2]=(short)f2bf(a2.z*inv); f1[3]=(short)f2bf(a2.w*inv);
        f1[4]=(short)f2bf(a3.x*inv); f1[5]=(short)f2bf(a3.y*inv);
        f1[6]=(short)f2bf(a3.z*inv); f1[7]=(short)f2bf(a3.w*inv);
        *(bf16x8*)&tnL[r * TNS + (seg << 4)]     = f0;
        *(bf16x8*)&tnL[r * TNS + (seg << 4) + 8] = f1;
    }
    __syncthreads();

    f32x4 acc2[4];   // wc^T: e = w*16+q*4+r, t = n*16+cl
#pragma unroll
    for (int n = 0; n < 4; ++n) acc2[n] = (f32x4){0.f,0.f,0.f,0.f};

    const unsigned short* vnb  = wsv + VN_OFF  + (long)b * S * E;
    const unsigned short* vntb = wsv + VNT_OFF + (long)b * E * S;
    float* attb = d_out + 1 + (long)b * (long)T * S;

    for (int ch = 0; ch < NCH; ++ch) {
        const int s0 = qt * SSEG + ch * CH;

        // ---- GEMM1 B-loads (global bf16, L2-hot) ----
        bf16x8 Bf[4];
        {
            const unsigned short* r0 = vnb + (long)(s0 + (w << 4) + cl) * E + (q << 3);
#pragma unroll
            for (int kk = 0; kk < 4; ++kk) Bf[kk] = *(const bf16x8*)(r0 + (kk << 5));
        }

        // ---- GEMM1 (A from LDS) + softmax -> ET ----
        {
            f32x4 acc1[4];
#pragma unroll
            for (int mt = 0; mt < 4; ++mt) acc1[mt] = (f32x4){0.f,0.f,0.f,0.f};
#pragma unroll
            for (int kk = 0; kk < 4; ++kk)
#pragma unroll
                for (int mt = 0; mt < 4; ++mt) {
                    const bf16x8 tA = *(const bf16x8*)&tnL[((mt << 4) + cl) * TNS + (kk << 5) + (q << 3)];
                    acc1[mt] = __builtin_amdgcn_mfma_f32_16x16x32_bf16(tA, Bf[kk], acc1[mt], 0, 0, 0);
                }
            float ex[4][4];
            float ssum = 0.f;
#pragma unroll
            for (int mt = 0; mt < 4; ++mt)
#pragma unroll
                for (int r = 0; r < 4; ++r) {
                    const float v = __expf(acc1[mt][r]);   // |logit| <= ~1: no max needed
                    ex[mt][r] = v; ssum += v;
                }
            ssum += __shfl_xor(ssum, 16);
            ssum += __shfl_xor(ssum, 32);
            const float csc = 4.0f / ssum;
            const int sloc = (w << 4) + cl;
#pragma unroll
            for (int mt = 0; mt < 4; ++mt)
#pragma unroll
                for (int r = 0; r < 4; ++r)
                    ET[((mt << 4) + (q << 2) + r) * ETS + sloc] = f2bf(__expf(ex[mt][r] * csc));
        }
        __syncthreads();

        // ---- GEMM2: wc^T += vnT (global b128) x ET (LDS b128) ----
        {
            const unsigned short* ar = vntb + (long)((w << 4) + cl) * S + s0 + (q << 3);
#pragma unroll
            for (int kk2 = 0; kk2 < 4; ++kk2) {
                const bf16x8 aV = *(const bf16x8*)(ar + (kk2 << 5));
#pragma unroll
                for (int n = 0; n < 4; ++n) {
                    const bf16x8 bE = *(const bf16x8*)&ET[((n << 4) + cl) * ETS + (kk2 << 5) + (q << 3)];
                    acc2[n] = __builtin_amdgcn_mfma_f32_16x16x32_bf16(aV, bE, acc2[n], 0, 0, 0);
                }
            }
        }

        // ---- diag: dump unnormalized e (att_norm self-normalizes) ----
        if (diag) {
            const int t = tid >> 3, sg = (tid & 7) << 4;
            float* ap = attb + (long)t * S + s0 + sg;
            const bf16x8 v0 = *(const bf16x8*)&ET[t * ETS + sg];
            const bf16x8 v1 = *(const bf16x8*)&ET[t * ETS + sg + 8];
#pragma unroll
            for (int j = 0; j < 8; ++j) {
                ap[j]     = bf2f((unsigned short)v0[j]);
                ap[8 + j] = bf2f((unsigned short)v1[j]);
            }
        }
        __syncthreads();
    }

    // ---- store wc^T partials (disjoint per (pair, quarter) — no atomics) ----
    {
        float* pp = wsf + WS_P + ((long)(((i << 4) + b) << 2) + qt) * 8192;
#pragma unroll
        for (int n = 0; n < 4; ++n)
#pragma unroll
            for (int r = 0; r < 4; ++r)
                pp[((w << 4) + (q << 2) + r) * 64 + (n << 4) + cl] = acc2[n][r];
    }
}

// Merged post-pass: blocks 0..1023 att row self-normalize; blocks 1024..1279
// reduce one pair (sum 4 quarters, cos over E, LSE over t -> sims). Independent.
__global__ __launch_bounds__(256, 4)
void post_kernel(float* __restrict__ d_out, const float* __restrict__ txt,
                 float* __restrict__ wsf)
{
    const int tid = threadIdx.x;
    if (blockIdx.x >= BS * T) {
        // ---- reduce pair ----
        __shared__ float sA[256], sB[256], sC[256];
        const int pair = blockIdx.x - BS * T;
        const int t = tid & 63, w4 = tid >> 6;
        const int i = pair >> 4, b = pair & 15;
        const float* p0 = wsf + WS_P + (long)pair * NSP * 8192;
        const float* tp = txt + ((long)i * T + t) * E + (w4 << 5);

        float ssq = 0.f, num = 0.f, w2 = 0.f;
#pragma unroll 8
        for (int e = 0; e < 32; ++e) {
            const float tv = tp[e];
            const int idx = ((w4 << 5) + e) * 64 + t;
            const float wc = p0[idx] + p0[idx + 8192] + p0[idx + 16384] + p0[idx + 24576];
            ssq = fmaf(tv, tv, ssq);
            num = fmaf(wc, tv, num);
            w2  = fmaf(wc, wc, w2);
        }
        sA[tid] = ssq; sB[tid] = num; sC[tid] = w2;
        __syncthreads();
        if (tid < 64) {
            const float ss = sA[tid] + sA[64 + tid] + sA[128 + tid] + sA[192 + tid];
            const float nm = sB[tid] + sB[64 + tid] + sB[128 + tid] + sB[192 + tid];
            const float ww = sC[tid] + sC[64 + tid] + sC[128 + tid] + sC[192 + tid];
            const float cosv = (nm / fmaxf(sqrtf(ss), 1e-12f)) / fmaxf(sqrtf(ww), 1e-20f);
            float r = __expf(5.0f * cosv);
#pragma unroll
            for (int m = 1; m < 64; m <<= 1) r += __shfl_xor(r, m);
            if (tid == 0) wsf[WS_SIMS + (b << 4) + i] = 10.0f * logf(r);
        }
        return;
    }
    // ---- att row (b,t): self-normalize in place ----
    __shared__ float r4[4];
    const int bt = blockIdx.x;
    float* p = d_out + 1 + (long)bt * 4096;
    float v[16];
    float s = 0.f;
#pragma unroll
    for (int k = 0; k < 16; ++k) { v[k] = p[k * 256 + tid]; s += v[k]; }
#pragma unroll
    for (int m = 1; m < 64; m <<= 1) s += __shfl_xor(s, m);
    if ((tid & 63) == 0) r4[tid >> 6] = s;
    __syncthreads();
    const float inv = 1.0f / (r4[0] + r4[1] + r4[2] + r4[3]);
#pragma unroll
    for (int k = 0; k < 16; ++k) p[k * 256 + tid] = v[k] * inv;
}

// Final 16x16 symmetric cross-entropy (needs all sims -> separate launch).
__global__ __launch_bounds__(256, 1)
void loss_kernel(const float* __restrict__ wsf, float* __restrict__ d_out)
{
    __shared__ float sm[16][17];
    __shared__ float red[16];
    const int tid = threadIdx.x;
    const int bb = tid >> 4, ii = tid & 15;
    const float x = wsf[WS_SIMS + bb * 16 + ii];
    sm[bb][ii] = x;
    float m = x;
#pragma unroll
    for (int msk = 1; msk < 16; msk <<= 1) m = fmaxf(m, __shfl_xor(m, msk));
    float s = __expf(x - m);
#pragma unroll
    for (int msk = 1; msk < 16; msk <<= 1) s += __shfl_xor(s, msk);
    const float lsm0 = x - m - logf(s);
    __syncthreads();
    const float y = sm[ii][bb];
    float m1 = y;
#pragma unroll
    for (int msk = 1; msk < 16; msk <<= 1) m1 = fmaxf(m1, __shfl_xor(m1, msk));
    float s1 = __expf(y - m1);
#pragma unroll
    for (int msk = 1; msk < 16; msk <<= 1) s1 += __shfl_xor(s1, msk);
    const float lsm1 = y - m1 - logf(s1);
    if (bb == ii) red[bb] = lsm0 + lsm1;
    __syncthreads();
    if (tid == 0) {
        float tot = 0.f;
#pragma unroll
        for (int k = 0; k < 16; ++k) tot += red[k];
        d_out[0] = -tot / 32.0f;
    }
}

extern "C" void kernel_launch(void* const* d_in, const int* in_sizes, int n_in,
                              void* d_out, int out_size, void* d_ws, size_t ws_size,
                              hipStream_t stream)
{
    const float* vis = (const float*)d_in[0];
    const float* txt = (const float*)d_in[1];
    float* out = (float*)d_out;
    unsigned short* wsv = (unsigned short*)d_ws;
    float* wsf = (float*)d_ws;

    hipLaunchKernelGGL(prep_kernel, dim3(512), dim3(512), 0, stream, vis, wsv);
    hipLaunchKernelGGL(clip_main_kernel, dim3(BS * BS * NSP), dim3(512), 0, stream,
                       wsv, txt, out, wsf);
    hipLaunchKernelGGL(post_kernel, dim3(BS * T + BS * BS), dim3(256), 0, stream,
                       out, txt, wsf);
    hipLaunchKernelGGL(loss_kernel, dim3(1), dim3(256), 0, stream, wsf, out);
}